// Round 12
// baseline (74.865 us; speedup 1.0000x reference)
//
#include <hip/hip_runtime.h>

#define BINS 256
#define BC_N 24   // B*C = 8*3
#define C_N  3
#define NROWS 12  // the row_sel = b*c bug uses only rows {0..8,10,12,14}
#define CHB  21   // hist blocks per (row,img): 21*12*2 = 504 = 2/CU (64KB LDS each)
#define ACH  128  // apply chunks

// ---------------------------------------------------------------------------
// Kernel 1: 256-bin histograms for the 12 USED rows of dst and ref.
// grid = (CHB, 12 compact rows, 2 images), block = 256, dynamic LDS = 64 KB.
//
// r2-r11 wall: LDS *atomics* serialize (~60 cyc/ds_add wave-instr, invariant
// to banking/replication/occupancy; ballot path caps at 0.75 px/cyc on VALU).
// Plain DS read/write is ~10x faster (m134: ~5.8 cyc/wave-instr). So: per-
// thread u8 counters, conflict-free layout h8[bin*256 + lane*4 + wave]
// (bank = lane%32, 2 lanes/bank = free), batched 4-read/4-write RMW per
// float4 with duplicate-increment correction (exact). Max 196 counts/byte.
// bin = floor(x*256) == trunc for x in [0,1); min-clamp for the 1.0 edge.
// ---------------------------------------------------------------------------
__global__ __launch_bounds__(256) void hm_hist(const float* __restrict__ dst,
                                               const float* __restrict__ refp,
                                               unsigned int* __restrict__ part,
                                               int n4_per_row) {
    extern __shared__ unsigned char h8[];     // 64 KB
    unsigned int* h32 = reinterpret_cast<unsigned int*>(h8);
    const int t = threadIdx.x;

    #pragma unroll
    for (int j = 0; j < 64; ++j) h32[j * 256 + t] = 0u;   // bank t%32: free
    __syncthreads();

    const int y = blockIdx.y;
    const int row = (y < 9) ? y : 2 * y - 8;  // {0..8,10,12,14}
    const float* img = blockIdx.z ? refp : dst;
    const float4* p = reinterpret_cast<const float4*>(img) + (size_t)row * n4_per_row;

    const int span = (n4_per_row + CHB - 1) / CHB;        // 12484
    const int lo = blockIdx.x * span;
    const int hi = min(lo + span, n4_per_row);
    // this thread's byte column: lane*4 + wave  (bank = lane%32)
    const unsigned off = (unsigned)(((t & 63) << 2) + (t >> 6));

    for (int i = lo + t; i < hi; i += 256) {
        float4 v = p[i];
        unsigned b0 = (unsigned)min((int)(v.x * 256.0f), 255);
        unsigned b1 = (unsigned)min((int)(v.y * 256.0f), 255);
        unsigned b2 = (unsigned)min((int)(v.z * 256.0f), 255);
        unsigned b3 = (unsigned)min((int)(v.w * 256.0f), 255);
        unsigned a0 = (b0 << 8) + off;
        unsigned a1 = (b1 << 8) + off;
        unsigned a2 = (b2 << 8) + off;
        unsigned a3 = (b3 << 8) + off;
        // hoist ALL reads before writes (addresses within the group that
        // collide are exactly the equal-bin ones; increments are corrected)
        unsigned r0 = h8[a0];
        unsigned r1 = h8[a1];
        unsigned r2 = h8[a2];
        unsigned r3 = h8[a3];
        unsigned i1 = 1u + (b1 == b0);
        unsigned i2 = 1u + (b2 == b0) + (b2 == b1);
        unsigned i3 = 1u + (b3 == b0) + (b3 == b1) + (b3 == b2);
        // writes in program order: for duplicate bins the LAST write carries
        // the full increment -> exact
        h8[a0] = (unsigned char)(r0 + 1u);
        h8[a1] = (unsigned char)(r1 + i1);
        h8[a2] = (unsigned char)(r2 + i2);
        h8[a3] = (unsigned char)(r3 + i3);
    }
    __syncthreads();

    // reduce: thread t sums bin t's 256 bytes (64 dwords), staggered banks
    const unsigned int* r32 = h32 + t * 64;
    unsigned a = 0, b = 0;
    #pragma unroll
    for (int k = 0; k < 64; ++k) {
        unsigned w = r32[(k + t) & 63];       // bank (k+t)%32: 2 lanes/bank
        a += w & 0x00FF00FFu;
        b += (w >> 8) & 0x00FF00FFu;
    }
    unsigned s = (a & 0xFFFFu) + (a >> 16) + (b & 0xFFFFu) + (b >> 16);
    part[(((size_t)blockIdx.z * NROWS + y) * CHB + blockIdx.x) * BINS + t] = s;
}

// ---------------------------------------------------------------------------
// Kernel 2: sum CHB per-block partials (exact integers), then the validated
// pipeline: integer Hillis-Steele scan (partials <= 2^20) -> CDF =
// cum/max(total,1e-12) (exact /2^20 -> bit-identical to np's sequential fp32
// cumsum) -> parallelized two-pointer:
//   s_i = searchsorted(cdf_ref, cdf_dst[i]); table[i]=max(1,s_i) before the
//   first failure; first fail poisons all later entries to 255.
// table[0]=0, table[255]=255. lut = table/255. grid = 12 blocks.
// ---------------------------------------------------------------------------
__global__ __launch_bounds__(256) void hm_table(const unsigned int* __restrict__ part,
                                                float* __restrict__ lut) {
    __shared__ unsigned int sd[BINS], sr[BINS];
    __shared__ float cdf_d[BINS], cdf_r[BINS];
    __shared__ int firstFail;

    const int r = blockIdx.x;                 // compact row
    const int t = threadIdx.x;

    const unsigned int* pd = part + ((size_t)0 * NROWS + r) * CHB * BINS;
    const unsigned int* pr = part + ((size_t)1 * NROWS + r) * CHB * BINS;
    unsigned int xd = 0, xr = 0;
    #pragma unroll
    for (int k = 0; k < CHB; ++k) {
        xd += pd[k * BINS + t];
        xr += pr[k * BINS + t];
    }
    if (t == 0) firstFail = BINS;
    sd[t] = xd; sr[t] = xr;
    __syncthreads();

    #pragma unroll
    for (int off = 1; off < BINS; off <<= 1) {
        unsigned int yd = (t >= off) ? sd[t - off] : 0u;
        unsigned int yr = (t >= off) ? sr[t - off] : 0u;
        __syncthreads();
        xd += yd; xr += yr;
        sd[t] = xd; sr[t] = xr;
        __syncthreads();
    }
    float totd = fmaxf((float)sd[BINS - 1], 1e-12f);
    float totr = fmaxf((float)sr[BINS - 1], 1e-12f);
    cdf_d[t] = (float)xd / totd;
    cdf_r[t] = (float)xr / totr;
    __syncthreads();

    int out;
    if (t == 0) {
        out = 0;
    } else {
        float d = cdf_d[t];
        int lo = 0, hi = BINS;                // searchsorted 'left' in [0,256]
        while (lo < hi) {
            int m = (lo + hi) >> 1;
            if (cdf_r[m] < d) lo = m + 1; else hi = m;
        }
        int cand = lo > 1 ? lo : 1;
        bool ok = (cand <= BINS - 1) && (d >= cdf_r[cand - 1]);
        if (!ok) atomicMin(&firstFail, t);
        out = cand;
    }
    __syncthreads();

    if (t >= firstFail) out = BINS - 1;
    if (t == BINS - 1) out = BINS - 1;
    lut[(size_t)r * BINS + t] = (float)out / 255.0f;
}

// ---------------------------------------------------------------------------
// Kernel 3 (r11-validated): apply LUT; preserves the reference's row_sel=b*c
// bug via compact mapping. pix = clip(trunc(dst*255),0,255).
// grid = (ACH=128, 24), block = 256, 2-deep load batching.
// ---------------------------------------------------------------------------
__global__ __launch_bounds__(256) void hm_apply(const float* __restrict__ dst,
                                                const float* __restrict__ lut,
                                                float* __restrict__ out,
                                                int n4_per_row) {
    __shared__ float slut[BINS];
    const int bc = blockIdx.y;
    const int b = bc / C_N;
    const int c = bc - b * C_N;
    const int r = b * c;                      // <-- preserved bug
    const int cr = (r <= 8) ? r : 8 + ((r - 8) >> 1);   // compact index
    const int t = threadIdx.x;

    slut[t] = lut[(size_t)cr * BINS + t];
    __syncthreads();

    const float4* in4 = reinterpret_cast<const float4*>(dst) + (size_t)bc * n4_per_row;
    float4* out4 = reinterpret_cast<float4*>(out) + (size_t)bc * n4_per_row;
    const int gsz = gridDim.x * 256;

    int i = blockIdx.x * 256 + t;
    for (; i + gsz < n4_per_row; i += 2 * gsz) {
        float4 v0 = in4[i];
        float4 v1 = in4[i + gsz];
        __builtin_amdgcn_sched_barrier(0);
        float4 o0, o1;
        o0.x = slut[min(max((int)(v0.x * 255.0f), 0), 255)];
        o0.y = slut[min(max((int)(v0.y * 255.0f), 0), 255)];
        o0.z = slut[min(max((int)(v0.z * 255.0f), 0), 255)];
        o0.w = slut[min(max((int)(v0.w * 255.0f), 0), 255)];
        o1.x = slut[min(max((int)(v1.x * 255.0f), 0), 255)];
        o1.y = slut[min(max((int)(v1.y * 255.0f), 0), 255)];
        o1.z = slut[min(max((int)(v1.z * 255.0f), 0), 255)];
        o1.w = slut[min(max((int)(v1.w * 255.0f), 0), 255)];
        out4[i] = o0;
        out4[i + gsz] = o1;
    }
    for (; i < n4_per_row; i += gsz) {
        float4 v = in4[i];
        float4 o;
        o.x = slut[min(max((int)(v.x * 255.0f), 0), 255)];
        o.y = slut[min(max((int)(v.y * 255.0f), 0), 255)];
        o.z = slut[min(max((int)(v.z * 255.0f), 0), 255)];
        o.w = slut[min(max((int)(v.w * 255.0f), 0), 255)];
        out4[i] = o;
    }
}

extern "C" void kernel_launch(void* const* d_in, const int* in_sizes, int n_in,
                              void* d_out, int out_size, void* d_ws, size_t ws_size,
                              hipStream_t stream) {
    const float* dst  = (const float*)d_in[0];
    const float* refp = (const float*)d_in[1];
    float* out = (float*)d_out;

    const int total = in_sizes[0];          // 8*3*1024*1024
    const int hw = total / BC_N;            // 1048576
    const int n4 = hw >> 2;                 // 262144 float4 per row

    // workspace: [part 2 x 12 x 21 x 256 u32 = 516 KB][lut 12x256 f32]
    unsigned int* part = (unsigned int*)d_ws;
    float* lut = (float*)((char*)d_ws + (size_t)2 * NROWS * CHB * BINS * sizeof(unsigned int));

    dim3 hg(CHB, NROWS, 2);
    hm_hist<<<hg, dim3(256), 65536, stream>>>(dst, refp, part, n4);

    hm_table<<<dim3(NROWS), dim3(256), 0, stream>>>(part, lut);

    dim3 ag(ACH, BC_N);
    hm_apply<<<ag, dim3(256), 0, stream>>>(dst, lut, out, n4);
}

// Round 13
// 65.789 us; speedup vs baseline: 1.1379x; 1.1379x over previous
//
#include <hip/hip_runtime.h>

#define BINS 256
#define BC_N 24   // B*C = 8*3
#define C_N  3
#define NROWS 12  // the row_sel = b*c bug uses only rows {0..8,10,12,14}
#define CH   85   // hist blocks per (row,img): 85*12*2 = 2040 = ~8/CU
#define ACH  128  // apply chunks

// ---------------------------------------------------------------------------
// Kernel 1: 256-bin histograms for the 12 USED rows of dst and ref.
// grid = (CH, 12 compact rows, 2 images), block = 256 (4 waves), 2 KB LDS.
//
// Final model (r2-r12): two counting mechanisms exist --
//   LDS atomic unit: ~1.1 atomic lane-ops/cyc/CU, needs ~24 feeder waves/CU
//     to saturate (r2); collapses to 0.58 at 15 feeders (r10/r11).
//   ballot bit-slicing: ~0.79 px/cyc/CU on the VALU at 24 waves (r6).
// This config saturates BOTH: 8 blocks/CU x {3 atomic waves + 1 ballot wave}
// = 24 feeders + 8 ballot waves per CU, pixel split 81:19 to balance
// completion times. Ballot segment is an exact multiple of 64 float4s (all
// lanes always valid -> no mask correction); atomic waves bounds-check.
// bin = floor(x*256) == trunc for x in [0,1); min-clamp for the 1.0 edge.
// ---------------------------------------------------------------------------
__global__ __launch_bounds__(256) void hm_hist(const float* __restrict__ dst,
                                               const float* __restrict__ refp,
                                               unsigned int* __restrict__ part,
                                               int n4_per_row) {
    __shared__ unsigned int shist[BINS];      // atomic-wave counts
    __shared__ unsigned int wsum[BINS];       // ballot-wave counts

    const int t = threadIdx.x;
    const int l = t & 63;
    const int w = t >> 6;                     // 0..3

    shist[t] = 0u;
    __syncthreads();

    const int y = blockIdx.y;
    const int row = (y < 9) ? y : 2 * y - 8;  // {0..8,10,12,14}
    const float* img = blockIdx.z ? refp : dst;
    const float4* p = reinterpret_cast<const float4*>(img) + (size_t)row * n4_per_row;

    const int span = (n4_per_row + CH - 1) / CH;         // 3085
    const int lo = blockIdx.x * span;
    const int hi = min(lo + span, n4_per_row);
    const int n  = hi - lo;
    const int SB = ((n * 19) / 100) & ~63;    // ballot segment: multiple of 64
    const int mid = hi - SB;                  // [lo,mid) atomic, [mid,hi) ballot

    if (w < 3) {
        // ----- 3 atomic-feeder waves: grid-stride 192 lanes, fire-and-forget -----
        for (int i = lo + w * 64 + l; i < mid; i += 192) {
            float4 v = p[i];
            atomicAdd(&shist[min((int)(v.x * 256.0f), 255)], 1u);
            atomicAdd(&shist[min((int)(v.y * 256.0f), 255)], 1u);
            atomicAdd(&shist[min((int)(v.z * 256.0f), 255)], 1u);
            atomicAdd(&shist[min((int)(v.w * 256.0f), 255)], 1u);
        }
    } else {
        // ----- 1 ballot wave: zero LDS in hot loop (r6-validated) -----
        const unsigned long long t0 = (l & 1)  ? 0ull : ~0ull;
        const unsigned long long t1 = (l & 2)  ? 0ull : ~0ull;
        const unsigned long long t2 = (l & 4)  ? 0ull : ~0ull;
        const unsigned long long t3 = (l & 8)  ? 0ull : ~0ull;
        const unsigned long long t4 = (l & 16) ? 0ull : ~0ull;
        const unsigned long long t5 = (l & 32) ? 0ull : ~0ull;
        unsigned int c0 = 0, c1 = 0, c2 = 0, c3 = 0;  // bins l,l+64,l+128,l+192

        auto grp = [&](float x) {
            int bin = min((int)(x * 256.0f), 255);
            unsigned long long B0 = __ballot(bin & 1);
            unsigned long long B1 = __ballot(bin & 2);
            unsigned long long B2 = __ballot(bin & 4);
            unsigned long long B3 = __ballot(bin & 8);
            unsigned long long B4 = __ballot(bin & 16);
            unsigned long long B5 = __ballot(bin & 32);
            unsigned long long B6 = __ballot(bin & 64);
            unsigned long long B7 = __ballot(bin & 128);
            unsigned long long m = (B0 ^ t0) & (B1 ^ t1) & (B2 ^ t2)
                                 & (B3 ^ t3) & (B4 ^ t4) & (B5 ^ t5);
            unsigned long long a = m & ~B7, b = m & B7;
            c0 += (unsigned)__popcll(a & ~B6);
            c1 += (unsigned)__popcll(a &  B6);
            c2 += (unsigned)__popcll(b & ~B6);
            c3 += (unsigned)__popcll(b &  B6);
        };

        const int nk = SB >> 6;               // 64-float4 groups, all lanes valid
        if (nk > 0) {
            float4 v = p[mid + l];
            for (int k = 0; k + 1 < nk; ++k) {
                float4 nv = p[mid + ((k + 1) << 6) + l];   // 1-deep prefetch
                __builtin_amdgcn_sched_barrier(0);
                grp(v.x); grp(v.y); grp(v.z); grp(v.w);
                v = nv;
            }
            grp(v.x); grp(v.y); grp(v.z); grp(v.w);
        }
        wsum[l]       = c0;                   // unconditional (c's may be 0)
        wsum[l + 64]  = c1;
        wsum[l + 128] = c2;
        wsum[l + 192] = c3;
    }
    __syncthreads();

    part[(((size_t)blockIdx.z * NROWS + y) * CH + blockIdx.x) * BINS + t]
        = shist[t] + wsum[t];
}

// ---------------------------------------------------------------------------
// Kernel 2: sum CH per-block partials (exact integers), then the validated
// pipeline: integer Hillis-Steele scan (partials <= 2^20) -> CDF =
// cum/max(total,1e-12) (exact /2^20 -> bit-identical to np's sequential fp32
// cumsum) -> parallelized two-pointer:
//   s_i = searchsorted(cdf_ref, cdf_dst[i]); table[i]=max(1,s_i) before the
//   first failure; first fail poisons all later entries to 255.
// table[0]=0, table[255]=255. lut = table/255. grid = 12 blocks.
// ---------------------------------------------------------------------------
__global__ __launch_bounds__(256) void hm_table(const unsigned int* __restrict__ part,
                                                float* __restrict__ lut) {
    __shared__ unsigned int sd[BINS], sr[BINS];
    __shared__ float cdf_d[BINS], cdf_r[BINS];
    __shared__ int firstFail;

    const int r = blockIdx.x;                 // compact row
    const int t = threadIdx.x;

    const unsigned int* pd = part + ((size_t)0 * NROWS + r) * CH * BINS;
    const unsigned int* pr = part + ((size_t)1 * NROWS + r) * CH * BINS;
    unsigned int xd = 0, xr = 0;
    #pragma unroll 5
    for (int k = 0; k < CH; ++k) {
        xd += pd[k * BINS + t];
        xr += pr[k * BINS + t];
    }
    if (t == 0) firstFail = BINS;
    sd[t] = xd; sr[t] = xr;
    __syncthreads();

    #pragma unroll
    for (int off = 1; off < BINS; off <<= 1) {
        unsigned int yd = (t >= off) ? sd[t - off] : 0u;
        unsigned int yr = (t >= off) ? sr[t - off] : 0u;
        __syncthreads();
        xd += yd; xr += yr;
        sd[t] = xd; sr[t] = xr;
        __syncthreads();
    }
    float totd = fmaxf((float)sd[BINS - 1], 1e-12f);
    float totr = fmaxf((float)sr[BINS - 1], 1e-12f);
    cdf_d[t] = (float)xd / totd;
    cdf_r[t] = (float)xr / totr;
    __syncthreads();

    int out;
    if (t == 0) {
        out = 0;
    } else {
        float d = cdf_d[t];
        int lo = 0, hi = BINS;                // searchsorted 'left' in [0,256]
        while (lo < hi) {
            int m = (lo + hi) >> 1;
            if (cdf_r[m] < d) lo = m + 1; else hi = m;
        }
        int cand = lo > 1 ? lo : 1;
        bool ok = (cand <= BINS - 1) && (d >= cdf_r[cand - 1]);
        if (!ok) atomicMin(&firstFail, t);
        out = cand;
    }
    __syncthreads();

    if (t >= firstFail) out = BINS - 1;
    if (t == BINS - 1) out = BINS - 1;
    lut[(size_t)r * BINS + t] = (float)out / 255.0f;
}

// ---------------------------------------------------------------------------
// Kernel 3 (r11-validated): apply LUT; preserves the reference's row_sel=b*c
// bug via compact mapping. pix = clip(trunc(dst*255),0,255).
// grid = (ACH=128, 24), block = 256, 2-deep load batching.
// ---------------------------------------------------------------------------
__global__ __launch_bounds__(256) void hm_apply(const float* __restrict__ dst,
                                                const float* __restrict__ lut,
                                                float* __restrict__ out,
                                                int n4_per_row) {
    __shared__ float slut[BINS];
    const int bc = blockIdx.y;
    const int b = bc / C_N;
    const int c = bc - b * C_N;
    const int r = b * c;                      // <-- preserved bug
    const int cr = (r <= 8) ? r : 8 + ((r - 8) >> 1);   // compact index
    const int t = threadIdx.x;

    slut[t] = lut[(size_t)cr * BINS + t];
    __syncthreads();

    const float4* in4 = reinterpret_cast<const float4*>(dst) + (size_t)bc * n4_per_row;
    float4* out4 = reinterpret_cast<float4*>(out) + (size_t)bc * n4_per_row;
    const int gsz = gridDim.x * 256;

    int i = blockIdx.x * 256 + t;
    for (; i + gsz < n4_per_row; i += 2 * gsz) {
        float4 v0 = in4[i];
        float4 v1 = in4[i + gsz];
        __builtin_amdgcn_sched_barrier(0);
        float4 o0, o1;
        o0.x = slut[min(max((int)(v0.x * 255.0f), 0), 255)];
        o0.y = slut[min(max((int)(v0.y * 255.0f), 0), 255)];
        o0.z = slut[min(max((int)(v0.z * 255.0f), 0), 255)];
        o0.w = slut[min(max((int)(v0.w * 255.0f), 0), 255)];
        o1.x = slut[min(max((int)(v1.x * 255.0f), 0), 255)];
        o1.y = slut[min(max((int)(v1.y * 255.0f), 0), 255)];
        o1.z = slut[min(max((int)(v1.z * 255.0f), 0), 255)];
        o1.w = slut[min(max((int)(v1.w * 255.0f), 0), 255)];
        out4[i] = o0;
        out4[i + gsz] = o1;
    }
    for (; i < n4_per_row; i += gsz) {
        float4 v = in4[i];
        float4 o;
        o.x = slut[min(max((int)(v.x * 255.0f), 0), 255)];
        o.y = slut[min(max((int)(v.y * 255.0f), 0), 255)];
        o.z = slut[min(max((int)(v.z * 255.0f), 0), 255)];
        o.w = slut[min(max((int)(v.w * 255.0f), 0), 255)];
        out4[i] = o;
    }
}

extern "C" void kernel_launch(void* const* d_in, const int* in_sizes, int n_in,
                              void* d_out, int out_size, void* d_ws, size_t ws_size,
                              hipStream_t stream) {
    const float* dst  = (const float*)d_in[0];
    const float* refp = (const float*)d_in[1];
    float* out = (float*)d_out;

    const int total = in_sizes[0];          // 8*3*1024*1024
    const int hw = total / BC_N;            // 1048576
    const int n4 = hw >> 2;                 // 262144 float4 per row

    // workspace: [part 2 x 12 x 85 x 256 u32 = 2.09 MB][lut 12x256 f32]
    unsigned int* part = (unsigned int*)d_ws;
    float* lut = (float*)((char*)d_ws + (size_t)2 * NROWS * CH * BINS * sizeof(unsigned int));

    dim3 hg(CH, NROWS, 2);
    hm_hist<<<hg, dim3(256), 0, stream>>>(dst, refp, part, n4);

    hm_table<<<dim3(NROWS), dim3(256), 0, stream>>>(part, lut);

    dim3 ag(ACH, BC_N);
    hm_apply<<<ag, dim3(256), 0, stream>>>(dst, lut, out, n4);
}